// Round 1
// baseline (32.676 us; speedup 1.0000x reference)
//
#include <hip/hip_runtime.h>

// SNN 2->8->8->1, 16 steps, leak=0.8, thr=0.5.
// R12 = hybrid LDS/VALU dv split. Model from R9-R11 history + arithmetic:
//   dur(25.2us) ~ VALU work (10.9us) + LDS-pipe work (~15us) with poor
//   overlap -> the loop's 9 ds_read/step ARE the long pole (consistent
//   with "VALU deletion null"). So: cut loop LDS 9 -> 4 reads/step.
//   - W_hh rows 0..3: half-size LDS lut, stride 5 (gcd(5,32)=1 -> spread)
//   - W_hh rows 4..7: in-register ascending-k fma chains, SGPR weights
//     (uniform s_load; v_fmac v,s,v = 1 sgpr read, legal)
//   - out-dot: luto[mk2] LDS read replaced by 8 cndmask(1.0)+8 fmac
//     (same VALU as the mk2 bit-pack it deletes; output update now
//     in-step since it is register-only)
// Predicted: 25.2 -> ~15-18us, bank-conflict ~0, VALUBusy up.
//
// Bit-exactness invariants (absmax 0.0 R1-R11, preserved):
//  - contract(off): a*b + c stays mul+add everywhere
//  - dots: ascending-k fma chain from 0, bits in {0.0,1.0}
//    (fma(0,w,acc)==acc, fma(1,w,acc)==RN(w+acc)) == lut construction
//  - reset (m>=0.5 ? 0 : m) == m*(1-s) bitwise
//  - L1 exactly periodic; F = 1 + #{t: c < B_t}, B_t constexpr bit-search
//  - unified LSB convention: neuron k = bit k everywhere

// ---- compile-time breakpoint search (bit-exact f32, IEEE RN per op) ----
constexpr bool spikes_by(float c, int p) {
    float m = 0.f;
    for (int t = 0; t < p; ++t) {
        float a = 0.8f * m;
        m = a + c;
        if (m >= 0.5f) return true;
    }
    return false;
}
constexpr unsigned find_B(int p) {
    unsigned lo = 0x3D4CCCCDu;  // 0.05f: never spikes
    unsigned hi = 0x3F19999Au;  // 0.6f : spikes at step 1
    while (hi - lo > 1u) {
        unsigned mid = lo + (hi - lo) / 2u;
        if (spikes_by(__builtin_bit_cast(float, mid), p)) hi = mid;
        else lo = mid;
    }
    return hi;
}
constexpr float kB[17] = {
    0.f,
    __builtin_bit_cast(float, find_B(1)),  __builtin_bit_cast(float, find_B(2)),
    __builtin_bit_cast(float, find_B(3)),  __builtin_bit_cast(float, find_B(4)),
    __builtin_bit_cast(float, find_B(5)),  __builtin_bit_cast(float, find_B(6)),
    __builtin_bit_cast(float, find_B(7)),  __builtin_bit_cast(float, find_B(8)),
    __builtin_bit_cast(float, find_B(9)),  __builtin_bit_cast(float, find_B(10)),
    __builtin_bit_cast(float, find_B(11)), __builtin_bit_cast(float, find_B(12)),
    __builtin_bit_cast(float, find_B(13)), __builtin_bit_cast(float, find_B(14)),
    __builtin_bit_cast(float, find_B(15)), __builtin_bit_cast(float, find_B(16))
};
constexpr unsigned mk_train(int F) {
    unsigned tr = 0;
    if (F <= 16) for (int t = F; t <= 16; t += F) tr |= 1u << (t - 1);
    return tr;
}
constexpr unsigned kTv[18] = {
    0, mk_train(1), mk_train(2),  mk_train(3),  mk_train(4),  mk_train(5),
    mk_train(6),  mk_train(7),  mk_train(8),  mk_train(9),  mk_train(10),
    mk_train(11), mk_train(12), mk_train(13), mk_train(14), mk_train(15),
    mk_train(16), mk_train(17)
};

__device__ __forceinline__ unsigned long long tr8(unsigned long long x) {
    unsigned long long t;
    t = (x ^ (x >> 7))  & 0x00AA00AA00AA00AAull; x = x ^ t ^ (t << 7);
    t = (x ^ (x >> 14)) & 0x0000CCCC0000CCCCull; x = x ^ t ^ (t << 14);
    t = (x ^ (x >> 28)) & 0x00000000F0F0F0F0ull; x = x ^ t ^ (t << 28);
    return x;
}

__global__ __launch_bounds__(256, 8) void snn_kernel(
    const float* __restrict__ x,
    const float* __restrict__ W_ih, const float* __restrict__ b_ih,
    const float* __restrict__ W_hh, const float* __restrict__ b_hh,
    const float* __restrict__ W_ho, const float* __restrict__ b_ho,
    float* __restrict__ out, int n)
{
#pragma clang fp contract(off)
    __shared__ float lut4[256 * 5];   // rows 0..3 of dv; stride 5 spreads banks
    __shared__ unsigned Tv[18];

    const int p = threadIdx.x;

    {   // lut4: entry q, rows j=0..3, exact full-width fma chains (k=0..7)
        float bits[8];
#pragma unroll
        for (int k = 0; k < 8; ++k) bits[k] = (float)((p >> k) & 1);
#pragma unroll
        for (int j = 0; j < 4; ++j) {
            float acc = 0.f;
#pragma unroll
            for (int k = 0; k < 8; ++k)
                acc = __fmaf_rn(bits[k], W_hh[8 * j + k], acc);
            lut4[p * 5 + j] = acc;    // bank (5p+j)%32: conflict-free write
        }
    }
    if (p < 18) Tv[p] = kTv[p];
    __syncthreads();

    const int i = blockIdx.x * 256 + p;
    if (i >= n) return;

    // Uniform weights -> SGPRs (scalar loads): W_hh rows 4..7, b_hh, W_ho, b_ho
    float whi[4][8];
#pragma unroll
    for (int j = 0; j < 4; ++j)
#pragma unroll
        for (int k = 0; k < 8; ++k)
            whi[j][k] = W_hh[8 * (4 + j) + k];
    float wo[8];
#pragma unroll
    for (int k = 0; k < 8; ++k) wo[k] = W_ho[k];
    float bh[8];
#pragma unroll
    for (int j = 0; j < 8; ++j) bh[j] = b_hh[j];
    const float bho = b_ho[0];

    const float2 xv = reinterpret_cast<const float2*>(x)[i];
    float cur[8];
#pragma unroll
    for (int j = 0; j < 8; ++j) {
        float d = __fmaf_rn(xv.y, W_ih[2 * j + 1], __fmul_rn(xv.x, W_ih[2 * j]));
        cur[j] = __fadd_rn(d, b_ih[j]);
    }

    // F = 1 + #{t: c < B_t}; B_t compile-time literals. train = Tv[F]
    unsigned trn[8];
#pragma unroll
    for (int j = 0; j < 8; ++j) {
        float c = cur[j];
        unsigned cnt = 0;
#pragma unroll
        for (int t = 1; t <= 16; ++t)
            cnt += (c < kB[t]) ? 1u : 0u;
        trn[j] = Tv[cnt + 1u];
    }

    // 8x16 bit transpose -> step bytes (byte t = step t, bit j = neuron j)
    unsigned long long A = 0, A2 = 0;
#pragma unroll
    for (int j = 0; j < 8; ++j) {
        A  |= (unsigned long long)(trn[j] & 0xFFu) << (8 * j);
        A2 |= (unsigned long long)((trn[j] >> 8) & 0xFFu) << (8 * j);
    }
    A = tr8(A); A2 = tr8(A2);

    float m2[8] = {0.f,0.f,0.f,0.f,0.f,0.f,0.f,0.f};
    float mo = 0.f;
    unsigned tot = 0;

    // prime: step-0 lut4 entry (4x b32 off one base, imm offsets)
    float dvL[4];
    unsigned bC;
    {
        bC = (unsigned)A & 0xFFu;
        A = (A >> 8) | (A2 << 56); A2 >>= 8;
        const float* e0 = &lut4[bC * 5];
#pragma unroll
        for (int j = 0; j < 4; ++j) dvL[j] = e0[j];
    }

#pragma unroll 1
    for (int t = 0; t < 16; ++t) {
        // byte for step t+1 (t=15 -> 0, harmless: reads entry 0)
        unsigned bN = (unsigned)A & 0xFFu;
        A = (A >> 8) | (A2 << 56); A2 >>= 8;

        // current byte's bits as exact {0.0f, 1.0f}  (bfe + cvt)
        float bf[8];
#pragma unroll
        for (int k = 0; k < 8; ++k) bf[k] = (float)((bC >> k) & 1u);

        // dv rows 4..7: ascending-k fma chains, SGPR weights (bit-exact
        // same op sequence the lut would have been built with)
        float dvH[4];
#pragma unroll
        for (int j = 0; j < 4; ++j) {
            float acc = 0.f;
#pragma unroll
            for (int k = 0; k < 8; ++k)
                acc = __fmaf_rn(bf[k], whi[j][k], acc);
            dvH[j] = acc;
        }

        // L2 update for step t (rows 0..3 from LDS prefetch, 4..7 from VALU)
        float bf2[8];
#pragma unroll
        for (int j = 0; j < 8; ++j) {
            float dv = (j < 4) ? dvL[j] : dvH[j - 4];
            float m = __fadd_rn(__fadd_rn(__fmul_rn(0.8f, m2[j]), dv), bh[j]);
            bool s = (m >= 0.5f);
            bf2[j] = s ? 1.0f : 0.0f;
            m2[j] = s ? 0.f : m;
        }

        // output dot: same ascending-k chain as the old luto construction
        float od = 0.f;
#pragma unroll
        for (int k = 0; k < 8; ++k)
            od = __fmaf_rn(bf2[k], wo[k], od);

        // output neuron update, in-step (register-only now)
        {
            float m = __fadd_rn(__fadd_rn(__fmul_rn(0.8f, mo), od), bho);
            bool s = (m >= 0.5f);
            tot += s ? 1u : 0u;
            mo = s ? 0.f : m;
        }

        // prefetch step t+1's lut4 entry (4x b32, stride 5)
        const float* en = &lut4[bN * 5];
#pragma unroll
        for (int j = 0; j < 4; ++j) dvL[j] = en[j];
        bC = bN;
    }

    out[i] = __fmul_rn((float)tot, 0.0625f);
}

extern "C" void kernel_launch(void* const* d_in, const int* in_sizes, int n_in,
                              void* d_out, int out_size, void* d_ws, size_t ws_size,
                              hipStream_t stream) {
    const float* x    = (const float*)d_in[0];
    const float* W_ih = (const float*)d_in[1];
    const float* b_ih = (const float*)d_in[2];
    const float* W_hh = (const float*)d_in[3];
    const float* b_hh = (const float*)d_in[4];
    const float* W_ho = (const float*)d_in[5];
    const float* b_ho = (const float*)d_in[6];
    float* out = (float*)d_out;

    const int n = out_size;  // 524288
    const int block = 256;
    const int grid = (n + block - 1) / block;  // 2048
    snn_kernel<<<grid, block, 0, stream>>>(x, W_ih, b_ih, W_hh, b_hh,
                                           W_ho, b_ho, out, n);
}

// Round 2
// 26.391 us; speedup vs baseline: 1.2382x; 1.2382x over previous
//
#include <hip/hip_runtime.h>

// SNN 2->8->8->1, 16 steps, leak=0.8, thr=0.5.
// R13 = R11 + two-deep LDS prefetch (dvA/dvB, unroll-2), REVERTING R12.
//
// R12 post-mortem: hybrid VALU split regressed 25.2 -> 32.7us. Removing
// LDS work bought ~0, added VALU cost full price (+ likely spills from
// 49 hoisted floats under the 64-VGPR launch_bounds cap). => the bound
// is NOT raw LDS bank work.
// Revised model: R11 issues the dv prefetch at loop BOTTOM and consumes
// at the NEXT TOP -- a ~10-instr window, and the single buffer's
// anti-dependence pins it there. Every step stalls on lgkmcnt for most
// of the LDS pipe time (~1670 cyc/step/CU for 288 gather reads) while
// VALU (~1040 cyc/step/CU) idles => per-step cost ~ LDS+VALU (sum),
// matching 25us. Fix: double-buffer, issue reads at sub-step TOP, one
// full sub-step (~60 instr) before consumption -> compiler emits counted
// lgkmcnt(8); per-step cost -> max(LDS, VALU).
// Predicted: 25.2 -> ~18-19us. +8 VGPR, no VALU change.
//
// Bit-exactness invariants (absmax 0.0 R1-R12, preserved):
//  - contract(off): a*b + c stays mul+add everywhere
//  - dots: ascending-k fma chain from 0, s in {0,1} (== plain-add accum)
//  - reset (m>=0.5 ? 0 : m) == m*(1-s) bitwise
//  - mo-chain and m2-chain are data-independent: moving the lagged mo
//    update before the L2 update is bitwise neutral
//  - L1 exactly periodic; F = 1 + #{t: c < B_t}, B_t constexpr bit-search
//  - unified LSB convention: neuron k = bit k in lut2/luto/mask/transpose

// ---- compile-time breakpoint search (bit-exact f32, IEEE RN per op) ----
constexpr bool spikes_by(float c, int p) {
    float m = 0.f;
    for (int t = 0; t < p; ++t) {
        float a = 0.8f * m;
        m = a + c;
        if (m >= 0.5f) return true;
    }
    return false;
}
constexpr unsigned find_B(int p) {
    unsigned lo = 0x3D4CCCCDu;  // 0.05f: never spikes
    unsigned hi = 0x3F19999Au;  // 0.6f : spikes at step 1
    while (hi - lo > 1u) {
        unsigned mid = lo + (hi - lo) / 2u;
        if (spikes_by(__builtin_bit_cast(float, mid), p)) hi = mid;
        else lo = mid;
    }
    return hi;
}
constexpr float kB[17] = {
    0.f,
    __builtin_bit_cast(float, find_B(1)),  __builtin_bit_cast(float, find_B(2)),
    __builtin_bit_cast(float, find_B(3)),  __builtin_bit_cast(float, find_B(4)),
    __builtin_bit_cast(float, find_B(5)),  __builtin_bit_cast(float, find_B(6)),
    __builtin_bit_cast(float, find_B(7)),  __builtin_bit_cast(float, find_B(8)),
    __builtin_bit_cast(float, find_B(9)),  __builtin_bit_cast(float, find_B(10)),
    __builtin_bit_cast(float, find_B(11)), __builtin_bit_cast(float, find_B(12)),
    __builtin_bit_cast(float, find_B(13)), __builtin_bit_cast(float, find_B(14)),
    __builtin_bit_cast(float, find_B(15)), __builtin_bit_cast(float, find_B(16))
};
constexpr unsigned mk_train(int F) {
    unsigned tr = 0;
    if (F <= 16) for (int t = F; t <= 16; t += F) tr |= 1u << (t - 1);
    return tr;
}
constexpr unsigned kTv[18] = {
    0, mk_train(1), mk_train(2),  mk_train(3),  mk_train(4),  mk_train(5),
    mk_train(6),  mk_train(7),  mk_train(8),  mk_train(9),  mk_train(10),
    mk_train(11), mk_train(12), mk_train(13), mk_train(14), mk_train(15),
    mk_train(16), mk_train(17)
};

__device__ __forceinline__ unsigned long long tr8(unsigned long long x) {
    unsigned long long t;
    t = (x ^ (x >> 7))  & 0x00AA00AA00AA00AAull; x = x ^ t ^ (t << 7);
    t = (x ^ (x >> 14)) & 0x0000CCCC0000CCCCull; x = x ^ t ^ (t << 14);
    t = (x ^ (x >> 28)) & 0x00000000F0F0F0F0ull; x = x ^ t ^ (t << 28);
    return x;
}

__global__ __launch_bounds__(256, 8) void snn_kernel(
    const float* __restrict__ x,
    const float* __restrict__ W_ih, const float* __restrict__ b_ih,
    const float* __restrict__ W_hh, const float* __restrict__ b_hh,
    const float* __restrict__ W_ho, const float* __restrict__ b_ho,
    float* __restrict__ out, int n)
{
#pragma clang fp contract(off)
    __shared__ float lut2[256 * 9];   // 9 KB, stride 9 (odd -> bank spread)
    __shared__ float luto[256];       // 1 KB
    __shared__ unsigned Tv[18];

    const int p = threadIdx.x;

    {   // lut2 + luto: entry q, neuron k at bit k (LSB), exact fma chains
        float bits[8];
#pragma unroll
        for (int k = 0; k < 8; ++k) bits[k] = (float)((p >> k) & 1);
#pragma unroll
        for (int j = 0; j < 8; ++j) {
            float acc = 0.f;
#pragma unroll
            for (int k = 0; k < 8; ++k)
                acc = __fmaf_rn(bits[k], W_hh[8 * j + k], acc);
            lut2[p * 9 + j] = acc;    // conflict-free: (9p+j) mod 32 spreads
        }
        float acc = 0.f;
#pragma unroll
        for (int k = 0; k < 8; ++k)
            acc = __fmaf_rn(bits[k], W_ho[k], acc);
        luto[p] = acc;
    }
    if (p < 18) Tv[p] = kTv[p];
    __syncthreads();

    const int i = blockIdx.x * 256 + p;
    if (i >= n) return;

    const float2 xv = reinterpret_cast<const float2*>(x)[i];
    float cur[8];
#pragma unroll
    for (int j = 0; j < 8; ++j) {
        float d = __fmaf_rn(xv.y, W_ih[2 * j + 1], __fmul_rn(xv.x, W_ih[2 * j]));
        cur[j] = __fadd_rn(d, b_ih[j]);
    }

    // F = 1 + #{t: c < B_t}; B_t compile-time literals. train = Tv[F]
    unsigned trn[8];
#pragma unroll
    for (int j = 0; j < 8; ++j) {
        float c = cur[j];
        unsigned cnt = 0;
#pragma unroll
        for (int t = 1; t <= 16; ++t)
            cnt += (c < kB[t]) ? 1u : 0u;
        trn[j] = Tv[cnt + 1u];
    }

    // 8x16 bit transpose -> step bytes (byte t = step t, bit j = neuron j)
    unsigned long long A = 0, A2 = 0;
#pragma unroll
    for (int j = 0; j < 8; ++j) {
        A  |= (unsigned long long)(trn[j] & 0xFFu) << (8 * j);
        A2 |= (unsigned long long)((trn[j] >> 8) & 0xFFu) << (8 * j);
    }
    A = tr8(A); A2 = tr8(A2);

    float bh[8];
#pragma unroll
    for (int j = 0; j < 8; ++j) bh[j] = b_hh[j];
    const float bho = b_ho[0];

    float m2[8] = {0.f,0.f,0.f,0.f,0.f,0.f,0.f,0.f};
    float mo = 0.f, outdot = 0.f;
    unsigned tot = 0;

    // prime: step-0 lut2 entry into dvA (8x b32 off one base, imm offsets)
    float dvA[8], dvB[8];
    {
        unsigned b0 = (unsigned)A & 0xFFu;
        A = (A >> 8) | (A2 << 56); A2 >>= 8;
        const float* e0 = &lut2[b0 * 9];
#pragma unroll
        for (int j = 0; j < 8; ++j) dvA[j] = e0[j];
    }

#pragma unroll 1
    for (int t = 0; t < 16; t += 2) {
        // ---- even sub-step: ISSUE dvB (step t+1), then consume dvA (t) ----
        {
            unsigned bN = (unsigned)A & 0xFFu;
            A = (A >> 8) | (A2 << 56); A2 >>= 8;
            const float* en = &lut2[bN * 9];
#pragma unroll
            for (int j = 0; j < 8; ++j) dvB[j] = en[j];   // in flight across this sub-step

            if (t > 0) {  // lagged output update (step t-1), independent of m2
                float m = __fadd_rn(__fadd_rn(__fmul_rn(0.8f, mo), outdot), bho);
                bool s = (m >= 0.5f);
                tot += s ? 1u : 0u;
                mo = s ? 0.f : m;
            }

            unsigned mk2 = 0;
#pragma unroll
            for (int j = 0; j < 8; ++j) {  // consumes dvA (issued one sub-step ago)
                float m = __fadd_rn(__fadd_rn(__fmul_rn(0.8f, m2[j]), dvA[j]), bh[j]);
                bool s = (m >= 0.5f);
                mk2 |= (s ? 1u : 0u) << j;
                m2[j] = s ? 0.f : m;
            }
            float nO = luto[mk2];          // step t out-dot (consumed next sub-step)
            outdot = nO;
        }
        // ---- odd sub-step: ISSUE dvA (step t+2), then consume dvB (t+1) ----
        {
            unsigned bN = (unsigned)A & 0xFFu;
            A = (A >> 8) | (A2 << 56); A2 >>= 8;
            const float* en = &lut2[bN * 9];
#pragma unroll
            for (int j = 0; j < 8; ++j) dvA[j] = en[j];   // t=14 -> byte 16 = 0, harmless

            {  // lagged output update (step t)
                float m = __fadd_rn(__fadd_rn(__fmul_rn(0.8f, mo), outdot), bho);
                bool s = (m >= 0.5f);
                tot += s ? 1u : 0u;
                mo = s ? 0.f : m;
            }

            unsigned mk2 = 0;
#pragma unroll
            for (int j = 0; j < 8; ++j) {  // consumes dvB
                float m = __fadd_rn(__fadd_rn(__fmul_rn(0.8f, m2[j]), dvB[j]), bh[j]);
                bool s = (m >= 0.5f);
                mk2 |= (s ? 1u : 0u) << j;
                m2[j] = s ? 0.f : m;
            }
            outdot = luto[mk2];            // step t+1 out-dot
        }
    }
    {   // final output update (step 15)
        float m = __fadd_rn(__fadd_rn(__fmul_rn(0.8f, mo), outdot), bho);
        tot += (m >= 0.5f) ? 1u : 0u;
    }

    out[i] = __fmul_rn((float)tot, 0.0625f);
}

extern "C" void kernel_launch(void* const* d_in, const int* in_sizes, int n_in,
                              void* d_out, int out_size, void* d_ws, size_t ws_size,
                              hipStream_t stream) {
    const float* x    = (const float*)d_in[0];
    const float* W_ih = (const float*)d_in[1];
    const float* b_ih = (const float*)d_in[2];
    const float* W_hh = (const float*)d_in[3];
    const float* b_hh = (const float*)d_in[4];
    const float* W_ho = (const float*)d_in[5];
    const float* b_ho = (const float*)d_in[6];
    float* out = (float*)d_out;

    const int n = out_size;  // 524288
    const int block = 256;
    const int grid = (n + block - 1) / block;  // 2048
    snn_kernel<<<grid, block, 0, stream>>>(x, W_ih, b_ih, W_hh, b_hh,
                                           W_ho, b_ho, out, n);
}